// Round 4
// baseline (661.056 us; speedup 1.0000x reference)
//
#include <hip/hip_runtime.h>
#include <hip/hip_bf16.h>
#include <cstdint>
#include <cstddef>

// Problem constants (B,S,E,H) = (8,4096,1024,1024)
static constexpr int Bb   = 8;
static constexpr int Ss   = 4096;
static constexpr int Ee   = 1024;
static constexpr int Hh   = 1024;
static constexpr int Mtot = Bb * Ss;      // 32768
static constexpr int NCH  = 32;           // scan chunks per sequence
static constexpr int SCH  = Ss / NCH;     // 128 steps per chunk

using f32x4 = __attribute__((ext_vector_type(4))) float;
using s16x8 = __attribute__((ext_vector_type(8))) short;
using u16x8 = __attribute__((ext_vector_type(8))) unsigned short;

__device__ __forceinline__ uint16_t f2bf(float f) {
  union { float f; uint32_t u; } c; c.f = f;
  uint32_t u = c.u;
  return (uint16_t)((u + 0x7FFFu + ((u >> 16) & 1u)) >> 16);  // RNE
}
__device__ __forceinline__ float bf2f(uint32_t lo16) {
  union { uint32_t u; float f; } c; c.u = lo16 << 16;
  return c.f;
}

// ---------------- cast x (f32) -> bf16 ----------------
__global__ void cast_x_kernel(const float* __restrict__ x,
                              uint16_t* __restrict__ xb, int n) {
  int stride = gridDim.x * blockDim.x * 8;
  for (int i = (blockIdx.x * blockDim.x + threadIdx.x) * 8; i < n; i += stride) {
    const float4* p = (const float4*)(x + i);
    float4 v0 = p[0];
    float4 v1 = p[1];
    u16x8 r;
    r[0] = f2bf(v0.x); r[1] = f2bf(v0.y); r[2] = f2bf(v0.z); r[3] = f2bf(v0.w);
    r[4] = f2bf(v1.x); r[5] = f2bf(v1.y); r[6] = f2bf(v1.z); r[7] = f2bf(v1.w);
    *(u16x8*)(xb + i) = r;
  }
}

// ---------------- transpose + cast weights: W(K,N) f32 -> Wt(N,K) bf16 ------
__global__ void wprep_kernel(const float* __restrict__ Wz,
                             const float* __restrict__ Wh,
                             const float* __restrict__ Wo,
                             uint16_t* __restrict__ Wzt,
                             uint16_t* __restrict__ Wht,
                             uint16_t* __restrict__ Wot) {
  __shared__ float tile[64][65];
  const float* src = (blockIdx.z == 0) ? Wz : (blockIdx.z == 1) ? Wh : Wo;
  uint16_t*    dst = (blockIdx.z == 0) ? Wzt : (blockIdx.z == 1) ? Wht : Wot;
  int k0 = blockIdx.x * 64, n0 = blockIdx.y * 64;
  int t = threadIdx.x;
  int c = t & 63, r0 = t >> 6;
  #pragma unroll
  for (int i = 0; i < 16; i++) {
    int r = r0 + i * 4;
    tile[r][c] = src[(size_t)(k0 + r) * 1024 + n0 + c];
  }
  __syncthreads();
  int k = t & 63, nn0 = t >> 6;
  #pragma unroll
  for (int i = 0; i < 16; i++) {
    int n = nn0 + i * 4;
    dst[(size_t)(n0 + n) * 1024 + k0 + k] = f2bf(tile[k][n]);
  }
}

// ---------------- MFMA GEMM: C = A(MxK) * Bt(NxK)^T ----------------
// DUAL: two B matrices (Wz,Wh), fused minGRU gate epilogue -> packed (c,v) bf16 pair.
// !DUAL: single B (Wo), epilogue adds bias, writes f32.
template <bool DUAL>
__global__ __launch_bounds__(256)
void gemm_kernel(const uint16_t* __restrict__ A,
                 const uint16_t* __restrict__ Bt0,
                 const uint16_t* __restrict__ Bt1,
                 const float* __restrict__ bias0,
                 const float* __restrict__ bias1,
                 uint32_t* __restrict__ cv_out,
                 float* __restrict__ out,
                 int M, int N, int K) {
  constexpr int LDT = 40;  // padded LDS row stride (bf16 elems) to spread banks
  __shared__ uint16_t As[128 * LDT];
  __shared__ uint16_t Bs0[64 * LDT];
  __shared__ uint16_t Bs1[DUAL ? 64 * LDT : 8];

  const int t = threadIdx.x;
  const int lane = t & 63, wid = t >> 6;
  const int wr = wid >> 1, wc = wid & 1;   // 2x2 wave grid; wave tile 64x32
  const int lr = lane & 15, kg = lane >> 4;
  const int m_base = blockIdx.x * 128;
  const int n_base = blockIdx.y * 64;

  f32x4 zero = {0.f, 0.f, 0.f, 0.f};
  f32x4 acc0[4][2];
  f32x4 acc1[DUAL ? 4 : 1][2];
  #pragma unroll
  for (int i = 0; i < 4; i++)
    #pragma unroll
    for (int j = 0; j < 2; j++) acc0[i][j] = zero;
  if constexpr (DUAL) {
    #pragma unroll
    for (int i = 0; i < 4; i++)
      #pragma unroll
      for (int j = 0; j < 2; j++) acc1[i][j] = zero;
  }

  for (int k0 = 0; k0 < K; k0 += 32) {
    // stage A tile: 128 rows x 32 bf16 (512 x 16B segments)
    #pragma unroll
    for (int i = 0; i < 2; i++) {
      int s = t + i * 256;
      int row = s >> 2, c16 = s & 3;
      s16x8 v = *(const s16x8*)(A + (size_t)(m_base + row) * K + k0 + c16 * 8);
      *(s16x8*)(As + row * LDT + c16 * 8) = v;
    }
    // stage B tile(s): 64 rows x 32 bf16 (256 x 16B segments)
    {
      int row = t >> 2, c16 = t & 3;
      s16x8 v = *(const s16x8*)(Bt0 + (size_t)(n_base + row) * K + k0 + c16 * 8);
      *(s16x8*)(Bs0 + row * LDT + c16 * 8) = v;
      if constexpr (DUAL) {
        s16x8 v1 = *(const s16x8*)(Bt1 + (size_t)(n_base + row) * K + k0 + c16 * 8);
        *(s16x8*)(Bs1 + row * LDT + c16 * 8) = v1;
      }
    }
    __syncthreads();

    s16x8 af[4], bf0[2], bf1[2];
    #pragma unroll
    for (int mf = 0; mf < 4; mf++)
      af[mf] = *(const s16x8*)(As + (wr * 64 + mf * 16 + lr) * LDT + kg * 8);
    #pragma unroll
    for (int nf = 0; nf < 2; nf++) {
      bf0[nf] = *(const s16x8*)(Bs0 + (wc * 32 + nf * 16 + lr) * LDT + kg * 8);
      if constexpr (DUAL)
        bf1[nf] = *(const s16x8*)(Bs1 + (wc * 32 + nf * 16 + lr) * LDT + kg * 8);
    }
    #pragma unroll
    for (int mf = 0; mf < 4; mf++)
      #pragma unroll
      for (int nf = 0; nf < 2; nf++) {
        acc0[mf][nf] = __builtin_amdgcn_mfma_f32_16x16x32_bf16(
            af[mf], bf0[nf], acc0[mf][nf], 0, 0, 0);
        if constexpr (DUAL)
          acc1[mf][nf] = __builtin_amdgcn_mfma_f32_16x16x32_bf16(
              af[mf], bf1[nf], acc1[mf][nf], 0, 0, 0);
      }
    __syncthreads();
  }

  // epilogue: C/D layout col = lane&15, row = (lane>>4)*4 + j  [m89-verified]
  #pragma unroll
  for (int mf = 0; mf < 4; mf++) {
    #pragma unroll
    for (int nf = 0; nf < 2; nf++) {
      #pragma unroll
      for (int j = 0; j < 4; j++) {
        int row = m_base + wr * 64 + mf * 16 + kg * 4 + j;
        int col = n_base + wc * 32 + nf * 16 + lr;
        if constexpr (DUAL) {
          float kv = acc0[mf][nf][j] + bias0[col];
          float av = acc1[mf][nf][j] + bias1[col];
          float zf = 1.f / (1.f + __expf(-kv));             // z = sigmoid(k)
          float cf = 1.f / (1.f + __expf(kv));              // coeff = sigmoid(-k)
          float gf = (av >= 0.f) ? (av + 0.5f)
                                 : (1.f / (1.f + __expf(-av)));  // g(a)
          float vf = zf * gf;
          cv_out[(size_t)row * N + col] =
              (uint32_t)f2bf(cf) | ((uint32_t)f2bf(vf) << 16);
        } else {
          out[(size_t)row * N + col] = acc0[mf][nf][j] + bias0[col];
        }
      }
    }
  }
  (void)Bt1; (void)bias1; (void)cv_out; (void)out;
}

// ---------------- scan pass 1: per-chunk (C,V) composition ----------------
__global__ void scan1_kernel(const uint32_t* __restrict__ cv,
                             float* __restrict__ Cc, float* __restrict__ Vc) {
  int h = blockIdx.x * 256 + threadIdx.x;
  int j = blockIdx.y, b = blockIdx.z;
  size_t base = ((size_t)b * Ss + (size_t)j * SCH) * Hh + h;
  float C = 1.f, V = 0.f;
  #pragma unroll 4
  for (int s = 0; s < SCH; s++) {
    uint32_t p = cv[base + (size_t)s * Hh];
    float c = bf2f(p & 0xFFFFu), v = bf2f(p >> 16);
    C *= c;
    V = fmaf(c, V, v);
  }
  size_t o = ((size_t)b * NCH + j) * Hh + h;
  Cc[o] = C;
  Vc[o] = V;
}

// ---------------- scan pass 2: cross-chunk scan + h_last output ----------------
__global__ void scan2_kernel(const float* __restrict__ h0,
                             const float* __restrict__ Cc,
                             const float* __restrict__ Vc,
                             float* __restrict__ hinit,
                             float* __restrict__ hlast) {
  int idx = blockIdx.x * 256 + threadIdx.x;  // b*H + h
  float x = h0[idx];
  float st = (x >= 0.f) ? (x + 0.5f) : (1.f / (1.f + __expf(-x)));  // g(h0)
  int b = idx >> 10, h = idx & 1023;
  for (int j = 0; j < NCH; j++) {
    size_t o = ((size_t)b * NCH + j) * Hh + h;
    hinit[o] = st;
    st = fmaf(Cc[o], st, Vc[o]);
  }
  hlast[idx] = st;
}

// ---------------- scan pass 3: materialize h (bf16) ----------------
__global__ void scan3_kernel(const uint32_t* __restrict__ cv,
                             const float* __restrict__ hinit,
                             uint16_t* __restrict__ hb) {
  int h = blockIdx.x * 256 + threadIdx.x;
  int j = blockIdx.y, b = blockIdx.z;
  size_t base = ((size_t)b * Ss + (size_t)j * SCH) * Hh + h;
  float st = hinit[((size_t)b * NCH + j) * Hh + h];
  #pragma unroll 4
  for (int s = 0; s < SCH; s++) {
    uint32_t p = cv[base + (size_t)s * Hh];
    st = fmaf(bf2f(p & 0xFFFFu), st, bf2f(p >> 16));
    hb[base + (size_t)s * Hh] = f2bf(st);
  }
}

extern "C" void kernel_launch(void* const* d_in, const int* in_sizes, int n_in,
                              void* d_out, int out_size, void* d_ws, size_t ws_size,
                              hipStream_t stream) {
  const float* x  = (const float*)d_in[0];
  const float* h0 = (const float*)d_in[1];
  const float* Wz = (const float*)d_in[2];
  const float* bz = (const float*)d_in[3];
  const float* Wh = (const float*)d_in[4];
  const float* bh = (const float*)d_in[5];
  const float* Wo = (const float*)d_in[6];
  const float* bo = (const float*)d_in[7];
  float* out = (float*)d_out;

  // cv (packed bf16 c,v) aliases d_out[0 .. Mtot*Hh*4): it is fully dead
  // before the final GEMM overwrites that region with `out`, and h_last
  // lives at the disjoint tail d_out + Mtot*Ee. Halves ws requirement.
  uint32_t* cv = (uint32_t*)d_out;

  // workspace layout (~143 MB total)
  char* p = (char*)d_ws;
  uint16_t* xb  = (uint16_t*)p; p += (size_t)Mtot * Ee * 2;   // 67 MB
  uint16_t* Wzt = (uint16_t*)p; p += (size_t)Ee * Hh * 2;     // 2 MB
  uint16_t* Wht = (uint16_t*)p; p += (size_t)Ee * Hh * 2;
  uint16_t* Wot = (uint16_t*)p; p += (size_t)Hh * Ee * 2;
  float* Cc     = (float*)p;    p += (size_t)Bb * NCH * Hh * 4;
  float* Vc     = (float*)p;    p += (size_t)Bb * NCH * Hh * 4;
  float* hinit  = (float*)p;    p += (size_t)Bb * NCH * Hh * 4;
  uint16_t* hb  = (uint16_t*)p; p += (size_t)Mtot * Hh * 2;   // 67 MB

  hipLaunchKernelGGL(cast_x_kernel, dim3(2048), dim3(256), 0, stream,
                     x, xb, Mtot * Ee);
  hipLaunchKernelGGL(wprep_kernel, dim3(16, 16, 3), dim3(256), 0, stream,
                     Wz, Wh, Wo, Wzt, Wht, Wot);
  hipLaunchKernelGGL((gemm_kernel<true>), dim3(Mtot / 128, Hh / 64), dim3(256), 0,
                     stream, xb, Wzt, Wht, bz, bh, cv, (float*)nullptr,
                     Mtot, Hh, Ee);
  hipLaunchKernelGGL(scan1_kernel, dim3(Hh / 256, NCH, Bb), dim3(256), 0, stream,
                     cv, Cc, Vc);
  hipLaunchKernelGGL(scan2_kernel, dim3((Bb * Hh) / 256), dim3(256), 0, stream,
                     h0, Cc, Vc, hinit, out + (size_t)Mtot * Ee);
  hipLaunchKernelGGL(scan3_kernel, dim3(Hh / 256, NCH, Bb), dim3(256), 0, stream,
                     cv, hinit, hb);
  hipLaunchKernelGGL((gemm_kernel<false>), dim3(Mtot / 128, Ee / 64), dim3(256), 0,
                     stream, hb, Wot, (const uint16_t*)nullptr, bo,
                     (const float*)nullptr, (uint32_t*)nullptr, out,
                     Mtot, Ee, Hh);
}

// Round 6
// 622.396 us; speedup vs baseline: 1.0621x; 1.0621x over previous
//
#include <hip/hip_runtime.h>
#include <hip/hip_bf16.h>
#include <cstdint>
#include <cstddef>

// Problem constants (B,S,E,H) = (8,4096,1024,1024)
static constexpr int Bb   = 8;
static constexpr int Ss   = 4096;
static constexpr int Ee   = 1024;
static constexpr int Hh   = 1024;
static constexpr int Mtot = Bb * Ss;      // 32768
static constexpr int NCH  = 32;           // scan chunks per sequence
static constexpr int SCH  = Ss / NCH;     // 128 steps per chunk

using f32x4 = __attribute__((ext_vector_type(4))) float;
using s16x8 = __attribute__((ext_vector_type(8))) short;
using u16x8 = __attribute__((ext_vector_type(8))) unsigned short;

__device__ __forceinline__ uint16_t f2bf(float f) {
  union { float f; uint32_t u; } c; c.f = f;
  uint32_t u = c.u;
  return (uint16_t)((u + 0x7FFFu + ((u >> 16) & 1u)) >> 16);  // RNE
}
__device__ __forceinline__ float bf2f(uint32_t lo16) {
  union { uint32_t u; float f; } c; c.u = lo16 << 16;
  return c.f;
}

// async global->LDS, 16B per lane; LDS dest = wave-uniform base + lane*16
#define GLOAD_LDS16(gp, lp)                                                  \
  __builtin_amdgcn_global_load_lds(                                          \
      (const __attribute__((address_space(1))) void*)(gp),                   \
      (__attribute__((address_space(3))) void*)(lp), 16, 0, 0)

// ---------------- cast x (f32) -> bf16 ----------------
__global__ void cast_x_kernel(const float* __restrict__ x,
                              uint16_t* __restrict__ xb, int n) {
  int stride = gridDim.x * blockDim.x * 8;
  for (int i = (blockIdx.x * blockDim.x + threadIdx.x) * 8; i < n; i += stride) {
    const float4* p = (const float4*)(x + i);
    float4 v0 = p[0];
    float4 v1 = p[1];
    u16x8 r;
    r[0] = f2bf(v0.x); r[1] = f2bf(v0.y); r[2] = f2bf(v0.z); r[3] = f2bf(v0.w);
    r[4] = f2bf(v1.x); r[5] = f2bf(v1.y); r[6] = f2bf(v1.z); r[7] = f2bf(v1.w);
    *(u16x8*)(xb + i) = r;
  }
}

// ---------------- transpose + cast weights: W(K,N) f32 -> Wt(N,K) bf16 ------
__global__ void wprep_kernel(const float* __restrict__ Wz,
                             const float* __restrict__ Wh,
                             const float* __restrict__ Wo,
                             uint16_t* __restrict__ Wzt,
                             uint16_t* __restrict__ Wht,
                             uint16_t* __restrict__ Wot) {
  __shared__ float tile[64][65];
  const float* src = (blockIdx.z == 0) ? Wz : (blockIdx.z == 1) ? Wh : Wo;
  uint16_t*    dst = (blockIdx.z == 0) ? Wzt : (blockIdx.z == 1) ? Wht : Wot;
  int k0 = blockIdx.x * 64, n0 = blockIdx.y * 64;
  int t = threadIdx.x;
  int c = t & 63, r0 = t >> 6;
  #pragma unroll
  for (int i = 0; i < 16; i++) {
    int r = r0 + i * 4;
    tile[r][c] = src[(size_t)(k0 + r) * 1024 + n0 + c];
  }
  __syncthreads();
  int k = t & 63, nn0 = t >> 6;
  #pragma unroll
  for (int i = 0; i < 16; i++) {
    int n = nn0 + i * 4;
    dst[(size_t)(n0 + n) * 1024 + k0 + k] = f2bf(tile[k][n]);
  }
}

// ---------------- MFMA GEMM, m97 structure ----------------
// Tile: 128(M) x NT(N per matrix), BK=32, 4 waves in 2x2, wave tile 64 x NT/2.
// Staging via global_load_lds (16B/lane) into LINEAR LDS [rows][32] bf16.
// DUAL: B0=Wz,B1=Wh (NT=64), fused gate epilogue -> packed (c,v) bf16 pair.
// !DUAL: B0=Wo (NT=128), bias epilogue, f32 out.
template <bool DUAL, int NT>
__global__ __launch_bounds__(256)
void gemm_kernel(const uint16_t* __restrict__ A,
                 const uint16_t* __restrict__ Bt0,
                 const uint16_t* __restrict__ Bt1,
                 const float* __restrict__ bias0,
                 const float* __restrict__ bias1,
                 uint32_t* __restrict__ cv_out,
                 float* __restrict__ out,
                 int M, int N, int K) {
  constexpr int NFR = NT / 32;  // N fragments per wave per matrix (2 or 4)
  __shared__ __align__(16) uint16_t As[128 * 32];
  __shared__ __align__(16) uint16_t Bs0[NT * 32];
  __shared__ __align__(16) uint16_t Bs1[DUAL ? NT * 32 : 8];

  const int t = threadIdx.x;
  const int lane = t & 63, wid = t >> 6;
  const int wr = wid >> 1, wc = wid & 1;
  const int lr = lane & 15, kg = lane >> 4;
  const int m_base = blockIdx.x * 128;
  const int n_base = blockIdx.y * NT;
  const int wcN = wc * (NT / 2);

  // staging: seg = j*256 + wid*64 + lane; row = seg>>2, kcol = (seg&3)*8
  const int srow = lane >> 2;
  const int scol = (lane & 3) * 8;
  const uint16_t* pA  = A   + (size_t)(m_base + wid * 16 + srow) * K + scol;
  const uint16_t* pB0 = Bt0 + (size_t)(n_base + wid * 16 + srow) * K + scol;
  const uint16_t* pB1 =
      DUAL ? (Bt1 + (size_t)(n_base + wid * 16 + srow) * K + scol) : nullptr;
  char* lA  = (char*)As  + wid * 1024;
  char* lB0 = (char*)Bs0 + wid * 1024;
  char* lB1 = (char*)Bs1 + wid * 1024;

  f32x4 zero = {0.f, 0.f, 0.f, 0.f};
  f32x4 acc0[4][NFR];
  f32x4 acc1[DUAL ? 4 : 1][NFR];
  #pragma unroll
  for (int i = 0; i < 4; i++)
    #pragma unroll
    for (int j = 0; j < NFR; j++) acc0[i][j] = zero;
  if constexpr (DUAL) {
    #pragma unroll
    for (int i = 0; i < 4; i++)
      #pragma unroll
      for (int j = 0; j < NFR; j++) acc1[i][j] = zero;
  }

  for (int k0 = 0; k0 < K; k0 += 32) {
    // A tile: 128x32 = 8KB = 2 wave-instrs per wave
    GLOAD_LDS16(pA + k0, lA);
    GLOAD_LDS16(pA + (size_t)64 * K + k0, lA + 4096);
    // B tile(s): NT x 32
    GLOAD_LDS16(pB0 + k0, lB0);
    if constexpr (NT == 128)
      GLOAD_LDS16(pB0 + (size_t)64 * K + k0, lB0 + 4096);
    if constexpr (DUAL) {
      GLOAD_LDS16(pB1 + k0, lB1);
      if constexpr (NT == 128)
        GLOAD_LDS16(pB1 + (size_t)64 * K + k0, lB1 + 4096);
    }
    __syncthreads();  // drains vmcnt before barrier

    s16x8 af[4], b0f[NFR], b1f[NFR];
    #pragma unroll
    for (int mf = 0; mf < 4; mf++)
      af[mf] = *(const s16x8*)(As + (wr * 64 + mf * 16 + lr) * 32 + kg * 8);
    #pragma unroll
    for (int nf = 0; nf < NFR; nf++) {
      b0f[nf] = *(const s16x8*)(Bs0 + (wcN + nf * 16 + lr) * 32 + kg * 8);
      if constexpr (DUAL)
        b1f[nf] = *(const s16x8*)(Bs1 + (wcN + nf * 16 + lr) * 32 + kg * 8);
    }
    #pragma unroll
    for (int mf = 0; mf < 4; mf++)
      #pragma unroll
      for (int nf = 0; nf < NFR; nf++) {
        acc0[mf][nf] = __builtin_amdgcn_mfma_f32_16x16x32_bf16(
            af[mf], b0f[nf], acc0[mf][nf], 0, 0, 0);
        if constexpr (DUAL)
          acc1[mf][nf] = __builtin_amdgcn_mfma_f32_16x16x32_bf16(
              af[mf], b1f[nf], acc1[mf][nf], 0, 0, 0);
      }
    __syncthreads();
  }

  // epilogue: C/D layout col = lane&15, row = (lane>>4)*4 + j  [m89-verified]
  #pragma unroll
  for (int mf = 0; mf < 4; mf++) {
    #pragma unroll
    for (int nf = 0; nf < NFR; nf++) {
      #pragma unroll
      for (int j = 0; j < 4; j++) {
        int row = m_base + wr * 64 + mf * 16 + kg * 4 + j;
        int col = n_base + wcN + nf * 16 + lr;
        if constexpr (DUAL) {
          float kv = acc0[mf][nf][j] + bias0[col];
          float av = acc1[mf][nf][j] + bias1[col];
          float zf = 1.f / (1.f + __expf(-kv));             // z = sigmoid(k)
          float cf = 1.f / (1.f + __expf(kv));              // coeff = sigmoid(-k)
          float gf = (av >= 0.f) ? (av + 0.5f)
                                 : (1.f / (1.f + __expf(-av)));  // g(a)
          float vf = zf * gf;
          cv_out[(size_t)row * N + col] =
              (uint32_t)f2bf(cf) | ((uint32_t)f2bf(vf) << 16);
        } else {
          out[(size_t)row * N + col] = acc0[mf][nf][j] + bias0[col];
        }
      }
    }
  }
  (void)pB1; (void)bias1; (void)cv_out; (void)out;
}

// ---------------- scan pass 1: per-chunk (C,V) composition ----------------
__global__ void scan1_kernel(const uint32_t* __restrict__ cv,
                             float* __restrict__ Cc, float* __restrict__ Vc) {
  int h = blockIdx.x * 256 + threadIdx.x;
  int j = blockIdx.y, b = blockIdx.z;
  size_t base = ((size_t)b * Ss + (size_t)j * SCH) * Hh + h;
  float C = 1.f, V = 0.f;
  #pragma unroll 4
  for (int s = 0; s < SCH; s++) {
    uint32_t p = cv[base + (size_t)s * Hh];
    float c = bf2f(p & 0xFFFFu), v = bf2f(p >> 16);
    C *= c;
    V = fmaf(c, V, v);
  }
  size_t o = ((size_t)b * NCH + j) * Hh + h;
  Cc[o] = C;
  Vc[o] = V;
}

// ---------------- scan pass 2: cross-chunk scan + h_last output ----------------
__global__ void scan2_kernel(const float* __restrict__ h0,
                             const float* __restrict__ Cc,
                             const float* __restrict__ Vc,
                             float* __restrict__ hinit,
                             float* __restrict__ hlast) {
  int idx = blockIdx.x * 256 + threadIdx.x;  // b*H + h
  float x = h0[idx];
  float st = (x >= 0.f) ? (x + 0.5f) : (1.f / (1.f + __expf(-x)));  // g(h0)
  int b = idx >> 10, h = idx & 1023;
  for (int j = 0; j < NCH; j++) {
    size_t o = ((size_t)b * NCH + j) * Hh + h;
    hinit[o] = st;
    st = fmaf(Cc[o], st, Vc[o]);
  }
  hlast[idx] = st;
}

// ---------------- scan pass 3: materialize h (bf16) ----------------
__global__ void scan3_kernel(const uint32_t* __restrict__ cv,
                             const float* __restrict__ hinit,
                             uint16_t* __restrict__ hb) {
  int h = blockIdx.x * 256 + threadIdx.x;
  int j = blockIdx.y, b = blockIdx.z;
  size_t base = ((size_t)b * Ss + (size_t)j * SCH) * Hh + h;
  float st = hinit[((size_t)b * NCH + j) * Hh + h];
  #pragma unroll 4
  for (int s = 0; s < SCH; s++) {
    uint32_t p = cv[base + (size_t)s * Hh];
    st = fmaf(bf2f(p & 0xFFFFu), st, bf2f(p >> 16));
    hb[base + (size_t)s * Hh] = f2bf(st);
  }
}

extern "C" void kernel_launch(void* const* d_in, const int* in_sizes, int n_in,
                              void* d_out, int out_size, void* d_ws, size_t ws_size,
                              hipStream_t stream) {
  const float* x  = (const float*)d_in[0];
  const float* h0 = (const float*)d_in[1];
  const float* Wz = (const float*)d_in[2];
  const float* bz = (const float*)d_in[3];
  const float* Wh = (const float*)d_in[4];
  const float* bh = (const float*)d_in[5];
  const float* Wo = (const float*)d_in[6];
  const float* bo = (const float*)d_in[7];
  float* out = (float*)d_out;

  // cv (packed bf16 c,v) aliases d_out[0 .. Mtot*Hh*4): it is fully dead
  // before the final GEMM overwrites that region with `out`, and h_last
  // lives at the disjoint tail d_out + Mtot*Ee.
  uint32_t* cv = (uint32_t*)d_out;

  // workspace layout (~143 MB total)
  char* p = (char*)d_ws;
  uint16_t* xb  = (uint16_t*)p; p += (size_t)Mtot * Ee * 2;   // 67 MB
  uint16_t* Wzt = (uint16_t*)p; p += (size_t)Ee * Hh * 2;     // 2 MB
  uint16_t* Wht = (uint16_t*)p; p += (size_t)Ee * Hh * 2;
  uint16_t* Wot = (uint16_t*)p; p += (size_t)Hh * Ee * 2;
  float* Cc     = (float*)p;    p += (size_t)Bb * NCH * Hh * 4;
  float* Vc     = (float*)p;    p += (size_t)Bb * NCH * Hh * 4;
  float* hinit  = (float*)p;    p += (size_t)Bb * NCH * Hh * 4;
  uint16_t* hb  = (uint16_t*)p; p += (size_t)Mtot * Hh * 2;   // 67 MB

  hipLaunchKernelGGL(cast_x_kernel, dim3(2048), dim3(256), 0, stream,
                     x, xb, Mtot * Ee);
  hipLaunchKernelGGL(wprep_kernel, dim3(16, 16, 3), dim3(256), 0, stream,
                     Wz, Wh, Wo, Wzt, Wht, Wot);
  hipLaunchKernelGGL((gemm_kernel<true, 64>), dim3(Mtot / 128, Hh / 64),
                     dim3(256), 0, stream, xb, Wzt, Wht, bz, bh, cv,
                     (float*)nullptr, Mtot, Hh, Ee);
  hipLaunchKernelGGL(scan1_kernel, dim3(Hh / 256, NCH, Bb), dim3(256), 0, stream,
                     cv, Cc, Vc);
  hipLaunchKernelGGL(scan2_kernel, dim3((Bb * Hh) / 256), dim3(256), 0, stream,
                     h0, Cc, Vc, hinit, out + (size_t)Mtot * Ee);
  hipLaunchKernelGGL(scan3_kernel, dim3(Hh / 256, NCH, Bb), dim3(256), 0, stream,
                     cv, hinit, hb);
  hipLaunchKernelGGL((gemm_kernel<false, 128>), dim3(Mtot / 128, Ee / 128),
                     dim3(256), 0, stream, hb, Wot, (const uint16_t*)nullptr,
                     bo, (const float*)nullptr, (uint32_t*)nullptr, out,
                     Mtot, Ee, Hh);
}

// Round 10
// 575.403 us; speedup vs baseline: 1.1489x; 1.0817x over previous
//
#include <hip/hip_runtime.h>
#include <hip/hip_bf16.h>
#include <cstdint>
#include <cstddef>

// Problem constants (B,S,E,H) = (8,4096,1024,1024)
static constexpr int Bb   = 8;
static constexpr int Ss   = 4096;
static constexpr int Ee   = 1024;
static constexpr int Hh   = 1024;
static constexpr int Mtot = Bb * Ss;      // 32768
static constexpr int NCH  = 32;           // scan chunks per sequence
static constexpr int SCH  = Ss / NCH;     // 128 steps per chunk

using f32x4 = __attribute__((ext_vector_type(4))) float;
using s16x8 = __attribute__((ext_vector_type(8))) short;
using u16x8 = __attribute__((ext_vector_type(8))) unsigned short;

__device__ __forceinline__ uint16_t f2bf(float f) {
  union { float f; uint32_t u; } c; c.f = f;
  uint32_t u = c.u;
  return (uint16_t)((u + 0x7FFFu + ((u >> 16) & 1u)) >> 16);  // RNE
}
__device__ __forceinline__ float bf2f(uint32_t lo16) {
  union { uint32_t u; float f; } c; c.u = lo16 << 16;
  return c.f;
}

// async global->LDS, 16B per lane; LDS dest = wave-uniform base + lane*16
#define GLOAD_LDS16(gp, lp)                                                  \
  __builtin_amdgcn_global_load_lds(                                          \
      (const __attribute__((address_space(1))) void*)(gp),                   \
      (__attribute__((address_space(3))) void*)(lp), 16, 0, 0)

// ---------------- cast x (f32) -> bf16 ----------------
__global__ void cast_x_kernel(const float* __restrict__ x,
                              uint16_t* __restrict__ xb, int n) {
  int stride = gridDim.x * blockDim.x * 8;
  for (int i = (blockIdx.x * blockDim.x + threadIdx.x) * 8; i < n; i += stride) {
    const float4* p = (const float4*)(x + i);
    float4 v0 = p[0];
    float4 v1 = p[1];
    u16x8 r;
    r[0] = f2bf(v0.x); r[1] = f2bf(v0.y); r[2] = f2bf(v0.z); r[3] = f2bf(v0.w);
    r[4] = f2bf(v1.x); r[5] = f2bf(v1.y); r[6] = f2bf(v1.z); r[7] = f2bf(v1.w);
    *(u16x8*)(xb + i) = r;
  }
}

// ---------------- transpose + cast weights: W(K,N) f32 -> Wt(N,K) bf16 ------
__global__ void wprep_kernel(const float* __restrict__ Wz,
                             const float* __restrict__ Wh,
                             const float* __restrict__ Wo,
                             uint16_t* __restrict__ Wzt,
                             uint16_t* __restrict__ Wht,
                             uint16_t* __restrict__ Wot) {
  __shared__ float tile[64][65];
  const float* src = (blockIdx.z == 0) ? Wz : (blockIdx.z == 1) ? Wh : Wo;
  uint16_t*    dst = (blockIdx.z == 0) ? Wzt : (blockIdx.z == 1) ? Wht : Wot;
  int k0 = blockIdx.x * 64, n0 = blockIdx.y * 64;
  int t = threadIdx.x;
  int c = t & 63, r0 = t >> 6;
  #pragma unroll
  for (int i = 0; i < 16; i++) {
    int r = r0 + i * 4;
    tile[r][c] = src[(size_t)(k0 + r) * 1024 + n0 + c];
  }
  __syncthreads();
  int k = t & 63, nn0 = t >> 6;
  #pragma unroll
  for (int i = 0; i < 16; i++) {
    int n = nn0 + i * 4;
    dst[(size_t)(n0 + n) * 1024 + k0 + k] = f2bf(tile[k][n]);
  }
}

// ---------------- MFMA GEMM, m97 structure ----------------
// Tile: 128(M) x NT(N per matrix), BK=32, 4 waves in 2x2, wave tile 64 x NT/2.
// Staging via global_load_lds (16B/lane) into LINEAR LDS [rows][32] bf16.
// 1-D grid, bijective XCD-chunked swizzle, y(N)-fastest block order so the
// 16 (or 8) blocks sharing an A-panel run adjacently on one XCD (L2 reuse).
// DUAL: B0=Wz,B1=Wh (NT=64), fused gate epilogue -> packed (c,v) bf16 pair.
// !DUAL: B0=Wo (NT=128), bias epilogue, f32 out.
template <bool DUAL, int NT, int KC>
__global__ __launch_bounds__(256)
void gemm_kernel(const uint16_t* __restrict__ A,
                 const uint16_t* __restrict__ Bt0,
                 const uint16_t* __restrict__ Bt1,
                 const float* __restrict__ bias0,
                 const float* __restrict__ bias1,
                 uint32_t* __restrict__ cv_out,
                 float* __restrict__ out,
                 int NYB, int N) {
  constexpr int NFR = NT / 32;  // N fragments per wave per matrix (2 or 4)
  __shared__ __align__(16) uint16_t As[128 * 32];
  __shared__ __align__(16) uint16_t Bs0[NT * 32];
  __shared__ __align__(16) uint16_t Bs1[DUAL ? NT * 32 : 8];

  // XCD-chunked bijective swizzle (gridDim.x % 8 == 0), then y-fastest.
  const int cpx = (int)gridDim.x >> 3;
  const int wg  = ((int)blockIdx.x & 7) * cpx + ((int)blockIdx.x >> 3);
  const int yb  = wg % NYB, xb = wg / NYB;

  const int t = threadIdx.x;
  const int lane = t & 63, wid = t >> 6;
  const int wr = wid >> 1, wc = wid & 1;
  const int lr = lane & 15, kg = lane >> 4;
  const int m_base = xb * 128;
  const int n_base = yb * NT;
  const int wcN = wc * (NT / 2);

  // staging: seg = j*256 + wid*64 + lane; row = seg>>2, kcol = (seg&3)*8
  const int srow = lane >> 2;
  const int scol = (lane & 3) * 8;
  const uint16_t* pA  = A   + (size_t)(m_base + wid * 16 + srow) * KC + scol;
  const uint16_t* pB0 = Bt0 + (size_t)(n_base + wid * 16 + srow) * KC + scol;
  const uint16_t* pB1 =
      DUAL ? (Bt1 + (size_t)(n_base + wid * 16 + srow) * KC + scol) : nullptr;
  char* lA  = (char*)As  + wid * 1024;
  char* lB0 = (char*)Bs0 + wid * 1024;
  char* lB1 = (char*)Bs1 + wid * 1024;

  f32x4 zero = {0.f, 0.f, 0.f, 0.f};
  f32x4 acc0[4][NFR];
  f32x4 acc1[DUAL ? 4 : 1][NFR];
  #pragma unroll
  for (int i = 0; i < 4; i++)
    #pragma unroll
    for (int j = 0; j < NFR; j++) acc0[i][j] = zero;
  if constexpr (DUAL) {
    #pragma unroll
    for (int i = 0; i < 4; i++)
      #pragma unroll
      for (int j = 0; j < NFR; j++) acc1[i][j] = zero;
  }

  #pragma unroll 8
  for (int k0 = 0; k0 < KC; k0 += 32) {
    // A tile: 128x32 = 8KB = 2 wave-instrs per wave
    GLOAD_LDS16(pA + k0, lA);
    GLOAD_LDS16(pA + (size_t)64 * KC + k0, lA + 4096);
    // B tile(s): NT x 32
    GLOAD_LDS16(pB0 + k0, lB0);
    if constexpr (NT == 128)
      GLOAD_LDS16(pB0 + (size_t)64 * KC + k0, lB0 + 4096);
    if constexpr (DUAL) {
      GLOAD_LDS16(pB1 + k0, lB1);
      if constexpr (NT == 128)
        GLOAD_LDS16(pB1 + (size_t)64 * KC + k0, lB1 + 4096);
    }
    __syncthreads();  // drains vmcnt before barrier

    s16x8 af[4], b0f[NFR], b1f[NFR];
    #pragma unroll
    for (int mf = 0; mf < 4; mf++)
      af[mf] = *(const s16x8*)(As + (wr * 64 + mf * 16 + lr) * 32 + kg * 8);
    #pragma unroll
    for (int nf = 0; nf < NFR; nf++) {
      b0f[nf] = *(const s16x8*)(Bs0 + (wcN + nf * 16 + lr) * 32 + kg * 8);
      if constexpr (DUAL)
        b1f[nf] = *(const s16x8*)(Bs1 + (wcN + nf * 16 + lr) * 32 + kg * 8);
    }
    #pragma unroll
    for (int mf = 0; mf < 4; mf++)
      #pragma unroll
      for (int nf = 0; nf < NFR; nf++) {
        acc0[mf][nf] = __builtin_amdgcn_mfma_f32_16x16x32_bf16(
            af[mf], b0f[nf], acc0[mf][nf], 0, 0, 0);
        if constexpr (DUAL)
          acc1[mf][nf] = __builtin_amdgcn_mfma_f32_16x16x32_bf16(
              af[mf], b1f[nf], acc1[mf][nf], 0, 0, 0);
      }
    __syncthreads();
  }

  // epilogue: C/D layout col = lane&15, row = (lane>>4)*4 + j  [m89-verified]
  #pragma unroll
  for (int mf = 0; mf < 4; mf++) {
    #pragma unroll
    for (int nf = 0; nf < NFR; nf++) {
      #pragma unroll
      for (int j = 0; j < 4; j++) {
        int row = m_base + wr * 64 + mf * 16 + kg * 4 + j;
        int col = n_base + wcN + nf * 16 + lr;
        if constexpr (DUAL) {
          float kv = acc0[mf][nf][j] + bias0[col];
          float av = acc1[mf][nf][j] + bias1[col];
          float ek = __expf(-kv);
          float zf = 1.f / (1.f + ek);                       // z  = sigmoid(k)
          float cf = ek * zf;                                // c  = sigmoid(-k)
          float gf = (av >= 0.f) ? (av + 0.5f)
                                 : (1.f / (1.f + __expf(-av)));  // g(a)
          float vf = zf * gf;
          cv_out[(size_t)row * N + col] =
              (uint32_t)f2bf(cf) | ((uint32_t)f2bf(vf) << 16);
        } else {
          out[(size_t)row * N + col] = acc0[mf][nf][j] + bias0[col];
        }
      }
    }
  }
  (void)pB1; (void)bias1; (void)cv_out; (void)out;
}

// ---------------- scan pass 1: per-chunk (C,V) composition ----------------
__global__ void scan1_kernel(const uint32_t* __restrict__ cv,
                             float* __restrict__ Cc, float* __restrict__ Vc) {
  int h = blockIdx.x * 256 + threadIdx.x;
  int j = blockIdx.y, b = blockIdx.z;
  size_t base = ((size_t)b * Ss + (size_t)j * SCH) * Hh + h;
  float C = 1.f, V = 0.f;
  #pragma unroll 4
  for (int s = 0; s < SCH; s++) {
    uint32_t p = cv[base + (size_t)s * Hh];
    float c = bf2f(p & 0xFFFFu), v = bf2f(p >> 16);
    C *= c;
    V = fmaf(c, V, v);
  }
  size_t o = ((size_t)b * NCH + j) * Hh + h;
  Cc[o] = C;
  Vc[o] = V;
}

// ---------------- scan pass 2: cross-chunk scan + h_last output ----------------
__global__ void scan2_kernel(const float* __restrict__ h0,
                             const float* __restrict__ Cc,
                             const float* __restrict__ Vc,
                             float* __restrict__ hinit,
                             float* __restrict__ hlast) {
  int idx = blockIdx.x * 256 + threadIdx.x;  // b*H + h
  float x = h0[idx];
  float st = (x >= 0.f) ? (x + 0.5f) : (1.f / (1.f + __expf(-x)));  // g(h0)
  int b = idx >> 10, h = idx & 1023;
  for (int j = 0; j < NCH; j++) {
    size_t o = ((size_t)b * NCH + j) * Hh + h;
    hinit[o] = st;
    st = fmaf(Cc[o], st, Vc[o]);
  }
  hlast[idx] = st;
}

// ---------------- scan pass 3: materialize h (bf16) ----------------
__global__ void scan3_kernel(const uint32_t* __restrict__ cv,
                             const float* __restrict__ hinit,
                             uint16_t* __restrict__ hb) {
  int h = blockIdx.x * 256 + threadIdx.x;
  int j = blockIdx.y, b = blockIdx.z;
  size_t base = ((size_t)b * Ss + (size_t)j * SCH) * Hh + h;
  float st = hinit[((size_t)b * NCH + j) * Hh + h];
  #pragma unroll 4
  for (int s = 0; s < SCH; s++) {
    uint32_t p = cv[base + (size_t)s * Hh];
    st = fmaf(bf2f(p & 0xFFFFu), st, bf2f(p >> 16));
    hb[base + (size_t)s * Hh] = f2bf(st);
  }
}

extern "C" void kernel_launch(void* const* d_in, const int* in_sizes, int n_in,
                              void* d_out, int out_size, void* d_ws, size_t ws_size,
                              hipStream_t stream) {
  const float* x  = (const float*)d_in[0];
  const float* h0 = (const float*)d_in[1];
  const float* Wz = (const float*)d_in[2];
  const float* bz = (const float*)d_in[3];
  const float* Wh = (const float*)d_in[4];
  const float* bh = (const float*)d_in[5];
  const float* Wo = (const float*)d_in[6];
  const float* bo = (const float*)d_in[7];
  float* out = (float*)d_out;

  // cv (packed bf16 c,v) aliases d_out[0 .. Mtot*Hh*4): it is fully dead
  // before the final GEMM overwrites that region with `out`, and h_last
  // lives at the disjoint tail d_out + Mtot*Ee.
  uint32_t* cv = (uint32_t*)d_out;

  // workspace layout (~143 MB total)
  char* p = (char*)d_ws;
  uint16_t* xb  = (uint16_t*)p; p += (size_t)Mtot * Ee * 2;   // 67 MB
  uint16_t* Wzt = (uint16_t*)p; p += (size_t)Ee * Hh * 2;     // 2 MB
  uint16_t* Wht = (uint16_t*)p; p += (size_t)Ee * Hh * 2;
  uint16_t* Wot = (uint16_t*)p; p += (size_t)Hh * Ee * 2;
  float* Cc     = (float*)p;    p += (size_t)Bb * NCH * Hh * 4;
  float* Vc     = (float*)p;    p += (size_t)Bb * NCH * Hh * 4;
  float* hinit  = (float*)p;    p += (size_t)Bb * NCH * Hh * 4;
  uint16_t* hb  = (uint16_t*)p; p += (size_t)Mtot * Hh * 2;   // 67 MB

  hipLaunchKernelGGL(cast_x_kernel, dim3(2048), dim3(256), 0, stream,
                     x, xb, Mtot * Ee);
  hipLaunchKernelGGL(wprep_kernel, dim3(16, 16, 3), dim3(256), 0, stream,
                     Wz, Wh, Wo, Wzt, Wht, Wot);
  // gemm<true>: grid = 256 x-panels * 16 y-blocks = 4096 (%8==0)
  hipLaunchKernelGGL((gemm_kernel<true, 64, 1024>),
                     dim3((Mtot / 128) * (Hh / 64)), dim3(256), 0, stream,
                     xb, Wzt, Wht, bz, bh, cv, (float*)nullptr,
                     Hh / 64, Hh);
  hipLaunchKernelGGL(scan1_kernel, dim3(Hh / 256, NCH, Bb), dim3(256), 0, stream,
                     cv, Cc, Vc);
  hipLaunchKernelGGL(scan2_kernel, dim3((Bb * Hh) / 256), dim3(256), 0, stream,
                     h0, Cc, Vc, hinit, out + (size_t)Mtot * Ee);
  hipLaunchKernelGGL(scan3_kernel, dim3(Hh / 256, NCH, Bb), dim3(256), 0, stream,
                     cv, hinit, hb);
  // gemm<false>: grid = 256 x-panels * 8 y-blocks = 2048 (%8==0)
  hipLaunchKernelGGL((gemm_kernel<false, 128, 1024>),
                     dim3((Mtot / 128) * (Ee / 128)), dim3(256), 0, stream,
                     hb, Wot, (const uint16_t*)nullptr, bo,
                     (const float*)nullptr, (uint32_t*)nullptr, out,
                     Ee / 128, Ee);
}

// Round 11
// 563.632 us; speedup vs baseline: 1.1728x; 1.0209x over previous
//
#include <hip/hip_runtime.h>
#include <hip/hip_bf16.h>
#include <cstdint>
#include <cstddef>

// Problem constants (B,S,E,H) = (8,4096,1024,1024)
static constexpr int Bb   = 8;
static constexpr int Ss   = 4096;
static constexpr int Ee   = 1024;
static constexpr int Hh   = 1024;
static constexpr int Mtot = Bb * Ss;      // 32768
static constexpr int NCH  = 32;           // scan chunks per sequence
static constexpr int SCH  = Ss / NCH;     // 128 steps per chunk (== GEMM M-tile)

using f32x4 = __attribute__((ext_vector_type(4))) float;
using s16x8 = __attribute__((ext_vector_type(8))) short;
using u16x8 = __attribute__((ext_vector_type(8))) unsigned short;

__device__ __forceinline__ uint16_t f2bf(float f) {
  union { float f; uint32_t u; } c; c.f = f;
  uint32_t u = c.u;
  return (uint16_t)((u + 0x7FFFu + ((u >> 16) & 1u)) >> 16);  // RNE
}
__device__ __forceinline__ float bf2f(uint32_t lo16) {
  union { uint32_t u; float f; } c; c.u = lo16 << 16;
  return c.f;
}

// async global->LDS, 16B per lane; LDS dest = wave-uniform base + lane*16
#define GLOAD_LDS16(gp, lp)                                                  \
  __builtin_amdgcn_global_load_lds(                                          \
      (const __attribute__((address_space(1))) void*)(gp),                   \
      (__attribute__((address_space(3))) void*)(lp), 16, 0, 0)

// ---------------- cast x (f32) -> bf16 ----------------
__global__ void cast_x_kernel(const float* __restrict__ x,
                              uint16_t* __restrict__ xb, int n) {
  int stride = gridDim.x * blockDim.x * 8;
  for (int i = (blockIdx.x * blockDim.x + threadIdx.x) * 8; i < n; i += stride) {
    const float4* p = (const float4*)(x + i);
    float4 v0 = p[0];
    float4 v1 = p[1];
    u16x8 r;
    r[0] = f2bf(v0.x); r[1] = f2bf(v0.y); r[2] = f2bf(v0.z); r[3] = f2bf(v0.w);
    r[4] = f2bf(v1.x); r[5] = f2bf(v1.y); r[6] = f2bf(v1.z); r[7] = f2bf(v1.w);
    *(u16x8*)(xb + i) = r;
  }
}

// ---------------- transpose + cast weights: W(K,N) f32 -> Wt(N,K) bf16 ------
__global__ void wprep_kernel(const float* __restrict__ Wz,
                             const float* __restrict__ Wh,
                             const float* __restrict__ Wo,
                             uint16_t* __restrict__ Wzt,
                             uint16_t* __restrict__ Wht,
                             uint16_t* __restrict__ Wot) {
  __shared__ float tile[64][65];
  const float* src = (blockIdx.z == 0) ? Wz : (blockIdx.z == 1) ? Wh : Wo;
  uint16_t*    dst = (blockIdx.z == 0) ? Wzt : (blockIdx.z == 1) ? Wht : Wot;
  int k0 = blockIdx.x * 64, n0 = blockIdx.y * 64;
  int t = threadIdx.x;
  int c = t & 63, r0 = t >> 6;
  #pragma unroll
  for (int i = 0; i < 16; i++) {
    int r = r0 + i * 4;
    tile[r][c] = src[(size_t)(k0 + r) * 1024 + n0 + c];
  }
  __syncthreads();
  int k = t & 63, nn0 = t >> 6;
  #pragma unroll
  for (int i = 0; i < 16; i++) {
    int n = nn0 + i * 4;
    dst[(size_t)(n0 + n) * 1024 + k0 + k] = f2bf(tile[k][n]);
  }
}

// ---------------- MFMA GEMM, m97 structure ----------------
// Tile: 128(M) x NT(N per matrix), BK=32, 4 waves in 2x2, wave tile 64 x NT/2.
// Staging via global_load_lds (16B/lane) into LINEAR LDS [rows][32] bf16.
// 1-D grid, bijective XCD-chunked swizzle, y(N)-fastest block order.
// DUAL: B0=Wz,B1=Wh (NT=64), fused gate epilogue -> packed (c,v) bf16 pair,
//       PLUS fused per-chunk (C,V) scan composition (block tile == one chunk):
//       composes f32 c,v over the 128 rows in row order via shfl butterflies,
//       writes Cc/Vc directly (replaces the old scan1 pass).
// !DUAL: B0=Wo (NT=128), bias epilogue, f32 out.
template <bool DUAL, int NT, int KC>
__global__ __launch_bounds__(256)
void gemm_kernel(const uint16_t* __restrict__ A,
                 const uint16_t* __restrict__ Bt0,
                 const uint16_t* __restrict__ Bt1,
                 const float* __restrict__ bias0,
                 const float* __restrict__ bias1,
                 uint32_t* __restrict__ cv_out,
                 float* __restrict__ out,
                 float* __restrict__ Cc,
                 float* __restrict__ Vc,
                 int NYB, int N) {
  constexpr int NFR = NT / 32;  // N fragments per wave per matrix (2 or 4)
  __shared__ __align__(16) uint16_t As[128 * 32];
  __shared__ __align__(16) uint16_t Bs0[NT * 32];
  __shared__ __align__(16) uint16_t Bs1[DUAL ? NT * 32 : 8];
  __shared__ float CompLds[DUAL ? 256 : 1];  // [wr][wc][nf][lr] x {C,V}

  // XCD-chunked bijective swizzle (gridDim.x % 8 == 0), then y-fastest.
  const int cpx = (int)gridDim.x >> 3;
  const int wg  = ((int)blockIdx.x & 7) * cpx + ((int)blockIdx.x >> 3);
  const int yb  = wg % NYB, xb = wg / NYB;

  const int t = threadIdx.x;
  const int lane = t & 63, wid = t >> 6;
  const int wr = wid >> 1, wc = wid & 1;
  const int lr = lane & 15, kg = lane >> 4;
  const int m_base = xb * 128;
  const int n_base = yb * NT;
  const int wcN = wc * (NT / 2);

  // staging: seg = j*256 + wid*64 + lane; row = seg>>2, kcol = (seg&3)*8
  const int srow = lane >> 2;
  const int scol = (lane & 3) * 8;
  const uint16_t* pA  = A   + (size_t)(m_base + wid * 16 + srow) * KC + scol;
  const uint16_t* pB0 = Bt0 + (size_t)(n_base + wid * 16 + srow) * KC + scol;
  const uint16_t* pB1 =
      DUAL ? (Bt1 + (size_t)(n_base + wid * 16 + srow) * KC + scol) : nullptr;
  char* lA  = (char*)As  + wid * 1024;
  char* lB0 = (char*)Bs0 + wid * 1024;
  char* lB1 = (char*)Bs1 + wid * 1024;

  f32x4 zero = {0.f, 0.f, 0.f, 0.f};
  f32x4 acc0[4][NFR];
  f32x4 acc1[DUAL ? 4 : 1][NFR];
  #pragma unroll
  for (int i = 0; i < 4; i++)
    #pragma unroll
    for (int j = 0; j < NFR; j++) acc0[i][j] = zero;
  if constexpr (DUAL) {
    #pragma unroll
    for (int i = 0; i < 4; i++)
      #pragma unroll
      for (int j = 0; j < NFR; j++) acc1[i][j] = zero;
  }

  #pragma unroll 8
  for (int k0 = 0; k0 < KC; k0 += 32) {
    // A tile: 128x32 = 8KB = 2 wave-instrs per wave
    GLOAD_LDS16(pA + k0, lA);
    GLOAD_LDS16(pA + (size_t)64 * KC + k0, lA + 4096);
    // B tile(s): NT x 32
    GLOAD_LDS16(pB0 + k0, lB0);
    if constexpr (NT == 128)
      GLOAD_LDS16(pB0 + (size_t)64 * KC + k0, lB0 + 4096);
    if constexpr (DUAL) {
      GLOAD_LDS16(pB1 + k0, lB1);
      if constexpr (NT == 128)
        GLOAD_LDS16(pB1 + (size_t)64 * KC + k0, lB1 + 4096);
    }
    __syncthreads();  // drains vmcnt before barrier

    s16x8 af[4], b0f[NFR], b1f[NFR];
    #pragma unroll
    for (int mf = 0; mf < 4; mf++)
      af[mf] = *(const s16x8*)(As + (wr * 64 + mf * 16 + lr) * 32 + kg * 8);
    #pragma unroll
    for (int nf = 0; nf < NFR; nf++) {
      b0f[nf] = *(const s16x8*)(Bs0 + (wcN + nf * 16 + lr) * 32 + kg * 8);
      if constexpr (DUAL)
        b1f[nf] = *(const s16x8*)(Bs1 + (wcN + nf * 16 + lr) * 32 + kg * 8);
    }
    #pragma unroll
    for (int mf = 0; mf < 4; mf++)
      #pragma unroll
      for (int nf = 0; nf < NFR; nf++) {
        acc0[mf][nf] = __builtin_amdgcn_mfma_f32_16x16x32_bf16(
            af[mf], b0f[nf], acc0[mf][nf], 0, 0, 0);
        if constexpr (DUAL)
          acc1[mf][nf] = __builtin_amdgcn_mfma_f32_16x16x32_bf16(
              af[mf], b1f[nf], acc1[mf][nf], 0, 0, 0);
      }
    __syncthreads();
  }

  // epilogue: C/D layout col = lane&15, row = (lane>>4)*4 + j  [m89-verified]
  if constexpr (DUAL) {
    // Running per-col composition over this block's 128 rows (= 1 chunk).
    // h' = c*h + v; combine(A then B): C = CA*CB, V = CB*VA + VB.
    float Cw[2] = {1.f, 1.f}, Vw[2] = {0.f, 0.f};
    #pragma unroll
    for (int mf = 0; mf < 4; mf++) {      // rows ascend with mf (x16)
      #pragma unroll
      for (int nf = 0; nf < 2; nf++) {
        float Cs = 1.f, Vs = 0.f;          // lane segment: rows kg*4 .. kg*4+3
        #pragma unroll
        for (int j = 0; j < 4; j++) {      // rows ascend with j
          int row = m_base + wr * 64 + mf * 16 + kg * 4 + j;
          int col = n_base + wcN + nf * 16 + lr;
          float kv = acc0[mf][nf][j] + bias0[col];
          float av = acc1[mf][nf][j] + bias1[col];
          float ek = __expf(-kv);
          float zf = 1.f / (1.f + ek);                       // z = sigmoid(k)
          float cf = ek * zf;                                // c = sigmoid(-k)
          float gf = (av >= 0.f) ? (av + 0.5f)
                                 : (1.f / (1.f + __expf(-av)));  // g(a)
          float vf = zf * gf;
          cv_out[(size_t)row * N + col] =
              (uint32_t)f2bf(cf) | ((uint32_t)f2bf(vf) << 16);
          Vs = fmaf(cf, Vs, vf);
          Cs *= cf;
        }
        // ordered butterfly across kg (row order == kg order)
        {
          float Co = __shfl_xor(Cs, 16), Vo = __shfl_xor(Vs, 16);
          bool later = (kg & 1) != 0;
          float CA = later ? Co : Cs, VA = later ? Vo : Vs;
          float CB = later ? Cs : Co, VB = later ? Vs : Vo;
          Cs = CA * CB; Vs = fmaf(CB, VA, VB);
        }
        {
          float Co = __shfl_xor(Cs, 32), Vo = __shfl_xor(Vs, 32);
          bool later = (kg & 2) != 0;
          float CA = later ? Co : Cs, VA = later ? Vo : Vs;
          float CB = later ? Cs : Co, VB = later ? Vs : Vo;
          Cs = CA * CB; Vs = fmaf(CB, VA, VB);
        }
        // append 16-row segment (mf ascending keeps row order)
        Vw[nf] = fmaf(Cs, Vw[nf], Vs);
        Cw[nf] = Cw[nf] * Cs;
      }
    }
    if (kg == 0) {
      #pragma unroll
      for (int nf = 0; nf < 2; nf++) {
        int idx = ((((wr * 2 + wc) * 2 + nf) * 16) + lr) * 2;
        CompLds[idx] = Cw[nf];
        CompLds[idx + 1] = Vw[nf];
      }
    }
    __syncthreads();
    if (wid == 0) {  // 64 lanes = 64 cols; combine wr=0 then wr=1, write
      int wc2 = lane >> 5, nf2 = (lane >> 4) & 1, lr2 = lane & 15;
      int i0 = ((((0 * 2 + wc2) * 2 + nf2) * 16) + lr2) * 2;
      int i1 = ((((1 * 2 + wc2) * 2 + nf2) * 16) + lr2) * 2;
      float C0 = CompLds[i0], V0 = CompLds[i0 + 1];
      float C1 = CompLds[i1], V1 = CompLds[i1 + 1];
      float C = C0 * C1, V = fmaf(C1, V0, V1);
      int col = n_base + wc2 * 32 + nf2 * 16 + lr2;
      size_t o = (size_t)xb * (size_t)N + col;  // xb == global chunk index
      Cc[o] = C;
      Vc[o] = V;
    }
  } else {
    #pragma unroll
    for (int mf = 0; mf < 4; mf++) {
      #pragma unroll
      for (int nf = 0; nf < NFR; nf++) {
        #pragma unroll
        for (int j = 0; j < 4; j++) {
          int row = m_base + wr * 64 + mf * 16 + kg * 4 + j;
          int col = n_base + wcN + nf * 16 + lr;
          out[(size_t)row * N + col] = acc0[mf][nf][j] + bias0[col];
        }
      }
    }
  }
  (void)pB1; (void)bias1; (void)cv_out; (void)out; (void)Cc; (void)Vc;
}

// ---------------- scan pass 2: cross-chunk scan + h_last output ----------------
__global__ void scan2_kernel(const float* __restrict__ h0,
                             const float* __restrict__ Cc,
                             const float* __restrict__ Vc,
                             float* __restrict__ hinit,
                             float* __restrict__ hlast) {
  int idx = blockIdx.x * 256 + threadIdx.x;  // b*H + h
  float x = h0[idx];
  float st = (x >= 0.f) ? (x + 0.5f) : (1.f / (1.f + __expf(-x)));  // g(h0)
  int b = idx >> 10, h = idx & 1023;
  for (int j = 0; j < NCH; j++) {
    size_t o = ((size_t)b * NCH + j) * Hh + h;
    hinit[o] = st;
    st = fmaf(Cc[o], st, Vc[o]);
  }
  hlast[idx] = st;
}

// ---------------- scan pass 3: materialize h (bf16), 2 h-chains/thread -------
__global__ void scan3_kernel(const uint32_t* __restrict__ cv,
                             const float* __restrict__ hinit,
                             uint16_t* __restrict__ hb) {
  int h2 = (blockIdx.x * 256 + threadIdx.x) * 2;
  int j = blockIdx.y, b = blockIdx.z;
  size_t base = ((size_t)b * Ss + (size_t)j * SCH) * Hh + h2;
  size_t io = ((size_t)b * NCH + j) * Hh + h2;
  float2 hi = *(const float2*)(hinit + io);
  float st0 = hi.x, st1 = hi.y;
  #pragma unroll 4
  for (int s = 0; s < SCH; s++) {
    uint2 p = *(const uint2*)(cv + base + (size_t)s * Hh);
    st0 = fmaf(bf2f(p.x & 0xFFFFu), st0, bf2f(p.x >> 16));
    st1 = fmaf(bf2f(p.y & 0xFFFFu), st1, bf2f(p.y >> 16));
    ushort2 o;
    o.x = f2bf(st0);
    o.y = f2bf(st1);
    *(ushort2*)(hb + base + (size_t)s * Hh) = o;
  }
}

extern "C" void kernel_launch(void* const* d_in, const int* in_sizes, int n_in,
                              void* d_out, int out_size, void* d_ws, size_t ws_size,
                              hipStream_t stream) {
  const float* x  = (const float*)d_in[0];
  const float* h0 = (const float*)d_in[1];
  const float* Wz = (const float*)d_in[2];
  const float* bz = (const float*)d_in[3];
  const float* Wh = (const float*)d_in[4];
  const float* bh = (const float*)d_in[5];
  const float* Wo = (const float*)d_in[6];
  const float* bo = (const float*)d_in[7];
  float* out = (float*)d_out;

  // cv (packed bf16 c,v) aliases d_out[0 .. Mtot*Hh*4): it is fully dead
  // before the final GEMM overwrites that region with `out`, and h_last
  // lives at the disjoint tail d_out + Mtot*Ee.
  uint32_t* cv = (uint32_t*)d_out;

  // workspace layout (~143 MB total)
  char* p = (char*)d_ws;
  uint16_t* xb  = (uint16_t*)p; p += (size_t)Mtot * Ee * 2;   // 67 MB
  uint16_t* Wzt = (uint16_t*)p; p += (size_t)Ee * Hh * 2;     // 2 MB
  uint16_t* Wht = (uint16_t*)p; p += (size_t)Ee * Hh * 2;
  uint16_t* Wot = (uint16_t*)p; p += (size_t)Hh * Ee * 2;
  float* Cc     = (float*)p;    p += (size_t)Bb * NCH * Hh * 4;
  float* Vc     = (float*)p;    p += (size_t)Bb * NCH * Hh * 4;
  float* hinit  = (float*)p;    p += (size_t)Bb * NCH * Hh * 4;
  uint16_t* hb  = (uint16_t*)p; p += (size_t)Mtot * Hh * 2;   // 67 MB

  hipLaunchKernelGGL(cast_x_kernel, dim3(2048), dim3(256), 0, stream,
                     x, xb, Mtot * Ee);
  hipLaunchKernelGGL(wprep_kernel, dim3(16, 16, 3), dim3(256), 0, stream,
                     Wz, Wh, Wo, Wzt, Wht, Wot);
  // gemm<true>: grid = 256 x-panels * 16 y-blocks = 4096 (%8==0)
  // fused epilogue also writes per-chunk Cc/Vc (old scan1 removed)
  hipLaunchKernelGGL((gemm_kernel<true, 64, 1024>),
                     dim3((Mtot / 128) * (Hh / 64)), dim3(256), 0, stream,
                     xb, Wzt, Wht, bz, bh, cv, (float*)nullptr,
                     Cc, Vc, Hh / 64, Hh);
  hipLaunchKernelGGL(scan2_kernel, dim3((Bb * Hh) / 256), dim3(256), 0, stream,
                     h0, Cc, Vc, hinit, out + (size_t)Mtot * Ee);
  hipLaunchKernelGGL(scan3_kernel, dim3(Hh / 512, NCH, Bb), dim3(256), 0, stream,
                     cv, hinit, hb);
  // gemm<false>: grid = 256 x-panels * 8 y-blocks = 2048 (%8==0)
  hipLaunchKernelGGL((gemm_kernel<false, 128, 1024>),
                     dim3((Mtot / 128) * (Ee / 128)), dim3(256), 0, stream,
                     hb, Wot, (const uint16_t*)nullptr, bo,
                     (const float*)nullptr, (uint32_t*)nullptr, out,
                     (float*)nullptr, (float*)nullptr, Ee / 128, Ee);
}